// Round 3
// baseline (283.847 us; speedup 1.0000x reference)
//
#include <hip/hip_runtime.h>
#include <hip/hip_bf16.h>

#define IDIM 256
#define GDIM 64
#define ODIM 512
#define KD   (IDIM * GDIM)
#define WS_NEED ((size_t)2 * ODIM * IDIM * GDIM * 2)   // 32 MB bf16 image

typedef __attribute__((ext_vector_type(8))) short bhalf8;
typedef __attribute__((ext_vector_type(4))) float fvec4;

#define INV2PI 0.15915494309189535f

static __device__ __forceinline__ short bf16b(float v) {
    __hip_bfloat16 hb = __float2bfloat16(v);
    short s; __builtin_memcpy(&s, &hb, 2); return s;
}

// ---- prep: coeffs f32 [z][o][i][g] -> ws bf16 image [(i,z)][o][128B row, XOR-swizzled] ----
__global__ void prep_b(const float* __restrict__ coeffs, short* __restrict__ ws) {
    const int b = blockIdx.x;          // 512 blocks: (z, i)
    const int z = b & 1, i = b >> 1;
    const int o = threadIdx.x;         // 512 threads: o-row (writes coalesced)
    const float* src = coeffs + ((size_t)z * ODIM + o) * KD + (size_t)i * GDIM;
    short* dst = ws + ((size_t)(i * 2 + z) * ODIM + o) * GDIM;
    const int swz = (o & 7) << 4;
#pragma unroll
    for (int j = 0; j < 8; ++j) {
        fvec4 v0 = ((const fvec4*)src)[j * 2];
        fvec4 v1 = ((const fvec4*)src)[j * 2 + 1];
        bhalf8 pk;
#pragma unroll
        for (int u = 0; u < 4; ++u) { pk[u] = bf16b(v0[u]); pk[4 + u] = bf16b(v1[u]); }
        *(bhalf8*)((char*)dst + ((j * 16) ^ swz)) = pk;
    }
}

__global__ void bias_init(const float* __restrict__ bias, float* __restrict__ out) {
    int idx = blockIdx.x * 256 + threadIdx.x;
    fvec4 bv = ((const fvec4*)bias)[idx & 127];
    ((fvec4*)out)[idx] = bv;
}

// Tile T in [0,64): i = i0 + (T>>1), z = T&1 (cos/sin). LDS buffer parity == z.
// Per tile: 2 phases (ksub 0/1), each {stage ∥ ds_read → lgkm → barrier → 32 MFMA}.
// B staged a full tile ahead via global_load_lds (USE_WS) or reg+cvt (fallback).
template<int USE_WS>
__global__ void __launch_bounds__(512, 2)
fkan_gemm(const float* __restrict__ x, const float* __restrict__ coeffs,
          const short* __restrict__ wsb, float* __restrict__ out) {
    __shared__ __align__(16) short A_lds[2][256 * 64];
    __shared__ __align__(16) short B_lds[2][256 * 64];

    const int bx = blockIdx.x;
    const int xcd = bx & 7, jj = bx >> 3;
    const int lg = xcd * 2 + (jj & 1);   // (ot,ks) pinned per-XCD: 4MB B slice fits L2
    const int mt = jj >> 1;
    const int ot = lg >> 3, ks = lg & 7;
    const int row0 = mt * 256, col0 = ot * 256;
    const int i0 = ks * 32;

    const int t = threadIdx.x;
    const int lane = t & 63, wid = t >> 6;
    const int wave_m = wid & 1, wave_n = wid >> 1;

    const int ar = t >> 1, h = t & 1;    // trig staging: row / k-half
    const int bo = t >> 1, bh = t & 1;   // fallback B staging: o-row / g-half

    const float* xp  = x + (size_t)(row0 + ar) * IDIM + i0;
    const float* cb0 = coeffs + (size_t)(col0 + bo) * KD + (size_t)bh * 32 + (size_t)i0 * 64;
    const float* cb1 = cb0 + (size_t)ODIM * KD;
    const short* wbase = wsb + (size_t)i0 * 2 * ODIM * GDIM + (size_t)col0 * GDIM + (size_t)t * 8;

    const int rAb = wave_m * 128 + (lane & 15);
    const int rBb = wave_n * 64 + (lane & 15);
    const int kl  = (lane >> 4) * 16;
    const int msk = (lane & 7) << 4;

    fvec4 acc[8][4];
#pragma unroll
    for (int a = 0; a < 8; ++a)
#pragma unroll
        for (int b = 0; b < 4; ++b) acc[a][b] = (fvec4)0.0f;

    bhalf8 cpk4[4], spk4[4];
    fvec4 breg[8];   // fallback only

    auto trig_chain = [&](float xv) {
        float rev = xv * INV2PI;
        float a1 = __builtin_amdgcn_fractf(rev);
        float c1 = __builtin_amdgcn_cosf(a1);
        float s1 = __builtin_amdgcn_sinf(a1);
        float C2 = 2.0f * c1;
        float cA, sA, cB, sB;
        if (h == 0) { cA = 1.0f; sA = 0.0f; cB = c1; sB = s1; }
        else {
            float a32 = __builtin_amdgcn_fractf(rev * 32.0f);
            float c32 = __builtin_amdgcn_cosf(a32);
            float s32 = __builtin_amdgcn_sinf(a32);
            cA = c32; sA = s32;
            cB = c1 * c32 - s1 * s32;
            sB = s1 * c32 + c1 * s32;
        }
#pragma unroll
        for (int p = 0; p < 4; ++p) {
            bhalf8 cpk, spk;
#pragma unroll
            for (int u = 0; u < 8; ++u) {
                cpk[u] = bf16b(cB); spk[u] = bf16b(sB);
                float cn = __builtin_fmaf(C2, cB, -cA);
                float sn = __builtin_fmaf(C2, sB, -sA);
                cA = cB; cB = cn; sA = sB; sB = sn;
            }
            cpk4[p] = cpk; spk4[p] = spk;
        }
    };

    auto writeA = [&](short* Ab, const bhalf8* cp) {
#pragma unroll
        for (int p = 0; p < 4; ++p)
            *(bhalf8*)((char*)Ab + (size_t)ar * 128 +
                       (((32 * h + 8 * p) * 2) ^ ((ar & 7) << 4))) = cp[p];
    };

    // USE_WS: 4x global_load_lds(16B) per tile -> B_lds[T1&1]; wave-uniform LDS dest.
    auto dmaB = [&](int T1) {
#pragma unroll
        for (int q = 0; q < 4; ++q)
            __builtin_amdgcn_global_load_lds(
                (const __attribute__((address_space(1))) unsigned int*)
                    (wbase + (size_t)T1 * ODIM * GDIM + q * 4096),
                (__attribute__((address_space(3))) unsigned int*)
                    &B_lds[T1 & 1][q * 4096 + wid * 512],
                16, 0, 0);
    };

    // fallback staging
    auto issueB = [&](int T1) {
        const fvec4* q = (const fvec4*)(((T1 & 1) ? cb1 : cb0) + (size_t)(T1 >> 1) * 64);
#pragma unroll
        for (int m = 0; m < 8; ++m) breg[m] = q[m];
    };
    auto writeB = [&](short* Bb) {
#pragma unroll
        for (int j2 = 0; j2 < 4; ++j2) {
            bhalf8 pk;
#pragma unroll
            for (int u = 0; u < 8; ++u) pk[u] = bf16b(breg[j2 * 2 + (u >> 2)][u & 3]);
            *(bhalf8*)((char*)Bb + (size_t)bo * 128 +
                       ((bh * 64 + j2 * 16) ^ ((bo & 7) << 4))) = pk;
        }
    };

    auto dsA = [&](bhalf8* af, const short* Ab, int ksub) {
#pragma unroll
        for (int fm = 0; fm < 8; ++fm)
            af[fm] = *(const bhalf8*)((const char*)Ab +
                (size_t)(rAb + fm * 16) * 128 + ((ksub * 64 + kl) ^ msk));
    };
    auto dsB = [&](bhalf8* bq, const short* Bb, int ksub) {
#pragma unroll
        for (int fn = 0; fn < 4; ++fn)
            bq[fn] = *(const bhalf8*)((const char*)Bb +
                (size_t)(rBb + fn * 16) * 128 + ((ksub * 64 + kl) ^ msk));
    };
    auto quad = [&](const bhalf8* af, const bhalf8* bq) {
#pragma unroll
        for (int fm = 0; fm < 8; ++fm)
#pragma unroll
            for (int fn = 0; fn < 4; ++fn)
                acc[fm][fn] = __builtin_amdgcn_mfma_f32_16x16x32_bf16(
                    af[fm], bq[fn], acc[fm][fn], 0, 0, 0);
    };

    bhalf8 af[8], bq[4];

#define FENCE_LG()  do { asm volatile("s_waitcnt lgkmcnt(0)" ::: "memory"); \
                         __builtin_amdgcn_sched_barrier(0); \
                         __builtin_amdgcn_s_barrier(); \
                         __builtin_amdgcn_sched_barrier(0); } while (0)
#define FENCE_ALL() do { asm volatile("s_waitcnt vmcnt(0) lgkmcnt(0)" ::: "memory"); \
                         __builtin_amdgcn_sched_barrier(0); \
                         __builtin_amdgcn_s_barrier(); \
                         __builtin_amdgcn_sched_barrier(0); } while (0)
#define MFMA32(KS)  do { __builtin_amdgcn_s_setprio(1); quad(af, bq); \
                         __builtin_amdgcn_s_setprio(0); (void)(KS); } while (0)

    // ---- prologue: stage tile 0 (cos, i0) ----
    float xcur = xp[0];
    float xnext = xp[1];
    if (USE_WS) dmaB(0); else issueB(0);
    trig_chain(xcur);
    writeA((short*)A_lds[0], cpk4);
    if (!USE_WS) writeB((short*)B_lds[0]);
    FENCE_ALL();

#pragma unroll 1
    for (int ii = 0; ii < 32; ++ii) {
        // ================= tile (ii, z=0): buffers [0], stage tile 2ii+1 -> [1] =====
        {
            const int T1 = 2 * ii + 1;
            if (USE_WS) dmaB(T1); else issueB(T1);
            dsA(af, A_lds[0], 0); dsB(bq, B_lds[0], 0);
            FENCE_LG();
            MFMA32(0);

            dsA(af, A_lds[0], 1); dsB(bq, B_lds[0], 1);
            writeA((short*)A_lds[1], spk4);          // sin_i for tile (ii,1)
            if (!USE_WS) writeB((short*)B_lds[1]);
            FENCE_ALL();                              // publish + DMA complete
            MFMA32(1);
        }
        // ================= tile (ii, z=1): buffers [1], stage tile 2ii+2 -> [0] =====
        {
            const bool more = (ii < 31);
            if (more) { if (USE_WS) dmaB(2 * ii + 2); else issueB(2 * ii + 2); }
            dsA(af, A_lds[1], 0); dsB(bq, B_lds[1], 0);
            if (more) trig_chain(xnext);              // cos/sin chains for i+1
            FENCE_LG();
            MFMA32(0);

            dsA(af, A_lds[1], 1); dsB(bq, B_lds[1], 1);
            if (more) writeA((short*)A_lds[0], cpk4); // cos_{i+1} for tile (ii+1,0)
            if (!USE_WS && more) writeB((short*)B_lds[0]);
            if (ii < 30) xnext = xp[ii + 2];
            FENCE_ALL();
            MFMA32(1);
        }
    }
#undef FENCE_LG
#undef FENCE_ALL
#undef MFMA32

    // epilogue: C/D layout col=lane&15, row=(lane>>4)*4+r
#pragma unroll
    for (int fm = 0; fm < 8; ++fm) {
#pragma unroll
        for (int fn = 0; fn < 4; ++fn) {
            int col = col0 + wave_n * 64 + fn * 16 + (lane & 15);
#pragma unroll
            for (int r = 0; r < 4; ++r) {
                int row = row0 + wave_m * 128 + fm * 16 + ((lane >> 4) * 4) + r;
                atomicAdd(&out[(size_t)row * ODIM + col], acc[fm][fn][r]);
            }
        }
    }
}

extern "C" void kernel_launch(void* const* d_in, const int* in_sizes, int n_in,
                              void* d_out, int out_size, void* d_ws, size_t ws_size,
                              hipStream_t stream) {
    (void)in_sizes; (void)n_in; (void)out_size;
    const float* x      = (const float*)d_in[0];
    const float* coeffs = (const float*)d_in[1];
    const float* bias   = (const float*)d_in[2];
    float* out = (float*)d_out;

    const bool use_ws = (ws_size >= WS_NEED) && (((uintptr_t)d_ws & 15) == 0);

    bias_init<<<dim3(2048), dim3(256), 0, stream>>>(bias, out);
    if (use_ws) {
        prep_b<<<dim3(512), dim3(512), 0, stream>>>(coeffs, (short*)d_ws);
        fkan_gemm<1><<<dim3(256), dim3(512), 0, stream>>>(x, coeffs, (const short*)d_ws, out);
    } else {
        fkan_gemm<0><<<dim3(256), dim3(512), 0, stream>>>(x, coeffs, nullptr, out);
    }
}

// Round 4
// 247.587 us; speedup vs baseline: 1.1465x; 1.1465x over previous
//
#include <hip/hip_runtime.h>
#include <hip/hip_bf16.h>

#define IDIM 256
#define GDIM 64
#define ODIM 512
#define KD   (IDIM * GDIM)
#define NTILE 512                          // 256 i x 2 halves
#define TILE_SHORTS (512 * 64)             // full-o tile in ws image
#define WS_NEED ((size_t)NTILE * TILE_SHORTS * 2)   // 32 MB bf16 image

typedef __attribute__((ext_vector_type(8))) short bhalf8;
typedef __attribute__((ext_vector_type(4))) float fvec4;
typedef __attribute__((ext_vector_type(4))) unsigned uvec4;

#define INV2PI 0.15915494309189535f

static __device__ __forceinline__ short bf16b(float v) {
    __hip_bfloat16 hb = __float2bfloat16(v);
    short s; __builtin_memcpy(&s, &hb, 2); return s;
}

static __device__ __forceinline__ unsigned cvtpk(float lo, float hi) {
    unsigned r;
    asm("v_cvt_pk_bf16_f32 %0, %1, %2" : "=v"(r) : "v"(lo), "v"(hi));
    return r;
}

// ws image: tile b=(i*2+h): row o (512), k 0..31 = cos coeffs g in [32h+1,32h+32],
// k 32..63 = sin coeffs same g. Rows 128 B, XOR-swizzled 16B granules (^(o&7)<<4).
__global__ void prep_b(const float* __restrict__ coeffs, short* __restrict__ ws) {
    const int b = blockIdx.x;          // 512: i*2+h
    const int i = b >> 1, h = b & 1;
    const int o = threadIdx.x;         // 512
    const float* c0 = coeffs + (size_t)o * KD + (size_t)i * GDIM + h * 32;
    short* dst = ws + ((size_t)b * 512 + o) * 64;
    const int swz = (o & 7) << 4;
#pragma unroll
    for (int z = 0; z < 2; ++z) {
        const float* cz = c0 + (size_t)z * ODIM * KD;
#pragma unroll
        for (int j = 0; j < 4; ++j) {
            fvec4 v0 = ((const fvec4*)cz)[j * 2];
            fvec4 v1 = ((const fvec4*)cz)[j * 2 + 1];
            bhalf8 pk;
#pragma unroll
            for (int u = 0; u < 4; ++u) { pk[u] = bf16b(v0[u]); pk[4 + u] = bf16b(v1[u]); }
            *(bhalf8*)((char*)dst + ((z * 64 + j * 16) ^ swz)) = pk;
        }
    }
}

__global__ void bias_init(const float* __restrict__ bias, float* __restrict__ out) {
    int idx = blockIdx.x * 256 + threadIdx.x;
    fvec4 bv = ((const fvec4*)bias)[idx & 127];
    ((fvec4*)out)[idx] = bv;
}

// 256 blocks: 16 mt x (2 ot x 8 ks). Per block: 256 rows x 256 cols, K-chunk 32 i's
// = 64 tiles. B: 3-buffer DMA pipeline, vmcnt(4) counted. A: in-register Chebyshev.
template<int USE_WS>
__global__ void __launch_bounds__(512, 2)
fkan_gemm(const float* __restrict__ x, const float* __restrict__ coeffs,
          const short* __restrict__ wsb, float* __restrict__ out) {
    __shared__ __align__(16) short B_lds[3][256 * 64];   // 96 KB
    __shared__ float xl[256][33];                        // 33 KB, pad vs bank conflicts

    const int bx = blockIdx.x;
    const int xcd = bx & 7, jj = bx >> 3;
    const int lg = xcd * 2 + (jj & 1);   // (ot,ks) pinned per-XCD for B L2 reuse
    const int mt = jj >> 1;
    const int ot = lg >> 3, ks = lg & 7;
    const int row0 = mt * 256, col0 = ot * 256;
    const int i0 = ks * 32;

    const int t = threadIdx.x;
    const int lane = t & 63, wid = t >> 6;
    const int wave_m = wid & 1, wave_n = wid >> 1;

    const int rBb = wave_n * 64 + (lane & 15);
    const int kl  = (lane >> 4) * 16;
    const int msk = (lane & 7) << 4;
    const int kq8 = (lane >> 4) * 8;
    const int rA0 = wave_m * 128 + (lane & 15);

    // ---- x panel -> LDS (read-only afterwards) ----
#pragma unroll
    for (int k2 = 0; k2 < 16; ++k2) {
        int idx = t + k2 * 512;
        int r = idx >> 5, c = idx & 31;
        xl[r][c] = x[(size_t)(row0 + r) * IDIM + i0 + c];
    }

    fvec4 acc[8][4];
#pragma unroll
    for (int a = 0; a < 8; ++a)
#pragma unroll
        for (int b = 0; b < 4; ++b) acc[a][b] = (fvec4)0.0f;

    auto dmaB = [&](int j) {
        const short* src = wsb + (size_t)(i0 * 2 + j) * TILE_SHORTS
                         + (size_t)col0 * 64 + (size_t)t * 8;
        const int bsel = j % 3;
#pragma unroll
        for (int q = 0; q < 4; ++q)
            __builtin_amdgcn_global_load_lds(
                (const __attribute__((address_space(1))) unsigned*)(src + q * 4096),
                (__attribute__((address_space(3))) unsigned*)
                    &B_lds[bsel][q * 4096 + wid * 512],
                16, 0, 0);
    };

    // fallback: stage tile T via regs+cvt (same LDS image format)
    auto stage_fb = [&](int T) {
        const int bsel = T % 3;
        const int i = i0 + (T >> 1), hh = T & 1;
        const int o = t >> 1, z = t & 1;
        const float* src = coeffs + ((size_t)z * ODIM + col0 + o) * KD
                         + (size_t)i * GDIM + hh * 32;
        char* drow = (char*)&B_lds[bsel][o * 64];
        const int swz = (o & 7) << 4;
#pragma unroll
        for (int j = 0; j < 4; ++j) {
            fvec4 v0 = ((const fvec4*)src)[j * 2];
            fvec4 v1 = ((const fvec4*)src)[j * 2 + 1];
            bhalf8 pk;
#pragma unroll
            for (int u = 0; u < 4; ++u) { pk[u] = bf16b(v0[u]); pk[4 + u] = bf16b(v1[u]); }
            *(bhalf8*)(drow + ((z * 64 + j * 16) ^ swz)) = pk;
        }
    };

    // ---- prologue ----
    if (USE_WS) {
        dmaB(0); dmaB(1);
        asm volatile("s_waitcnt vmcnt(4) lgkmcnt(0)" ::: "memory");
        __builtin_amdgcn_s_barrier();
    } else {
        __syncthreads();
    }

#pragma unroll 1
    for (int T = 0; T < 64; ++T) {
        const int bsel = T % 3;
        if (USE_WS) {
            int j = T + 2; if (j > 63) j = 63;   // clamped re-DMA: idempotent, keeps vmcnt uniform
            dmaB(j);
            __builtin_amdgcn_sched_barrier(0);
        } else {
            stage_fb(T);
            __syncthreads();
        }

        const short* Bb = &B_lds[bsel][0];
        const int icur = T >> 1;
        const float g0f = (float)((T & 1) * 32 + kq8);

        // B fragments: 8 x ds_read_b128 (the only per-tile LDS reads)
        bhalf8 bq[4][2];
#pragma unroll
        for (int fn = 0; fn < 4; ++fn)
#pragma unroll
            for (int ksb = 0; ksb < 2; ++ksb)
                bq[fn][ksb] = *(const bhalf8*)((const char*)Bb +
                    (size_t)(rBb + fn * 16) * 128 + ((ksb * 64 + kl) ^ msk));

#pragma unroll
        for (int hm = 0; hm < 2; ++hm) {
            bhalf8 afc[4], afs[4];
#pragma unroll
            for (int q = 0; q < 4; ++q) {
                const int rxl = rA0 + (hm * 4 + q) * 16;
                float xv = xl[rxl][icur];
                float rev = xv * INV2PI;
                float a0 = __builtin_amdgcn_fractf(rev * g0f);
                float c0 = __builtin_amdgcn_cosf(a0);
                float s0 = __builtin_amdgcn_sinf(a0);
                float a1 = __builtin_amdgcn_fractf(rev);
                float c1 = __builtin_amdgcn_cosf(a1);
                float s1 = __builtin_amdgcn_sinf(a1);
                float C2 = c1 + c1;
                float cA = c0, sA = s0;
                float cB = c0 * c1 - s0 * s1;     // cos((g0+1)x)
                float sB = s0 * c1 + c0 * s1;
                unsigned pc[4], ps[4];
#pragma unroll
                for (int p = 0; p < 4; ++p) {
                    float cl = cB, sl = sB;
                    float cn = __builtin_fmaf(C2, cB, -cA);
                    float sn = __builtin_fmaf(C2, sB, -sA);
                    cA = cB; cB = cn; sA = sB; sB = sn;
                    pc[p] = cvtpk(cl, cB);
                    ps[p] = cvtpk(sl, sB);
                    cn = __builtin_fmaf(C2, cB, -cA);
                    sn = __builtin_fmaf(C2, sB, -sA);
                    cA = cB; cB = cn; sA = sB; sB = sn;
                }
                uvec4 uc = {pc[0], pc[1], pc[2], pc[3]};
                uvec4 us = {ps[0], ps[1], ps[2], ps[3]};
                afc[q] = __builtin_bit_cast(bhalf8, uc);
                afs[q] = __builtin_bit_cast(bhalf8, us);
            }
            __builtin_amdgcn_s_setprio(1);
#pragma unroll
            for (int q = 0; q < 4; ++q)
#pragma unroll
                for (int fn = 0; fn < 4; ++fn) {
                    acc[hm * 4 + q][fn] = __builtin_amdgcn_mfma_f32_16x16x32_bf16(
                        afc[q], bq[fn][0], acc[hm * 4 + q][fn], 0, 0, 0);
                    acc[hm * 4 + q][fn] = __builtin_amdgcn_mfma_f32_16x16x32_bf16(
                        afs[q], bq[fn][1], acc[hm * 4 + q][fn], 0, 0, 0);
                }
            __builtin_amdgcn_s_setprio(0);
        }

        if (USE_WS) {
            asm volatile("s_waitcnt vmcnt(4)" ::: "memory");   // counted: T+1 ready, T+2 in flight
            __builtin_amdgcn_s_barrier();
        } else {
            __syncthreads();
        }
    }

    // epilogue: C/D layout col=lane&15, row=(lane>>4)*4+r
#pragma unroll
    for (int fm = 0; fm < 8; ++fm) {
#pragma unroll
        for (int fn = 0; fn < 4; ++fn) {
            int col = col0 + wave_n * 64 + fn * 16 + (lane & 15);
#pragma unroll
            for (int r = 0; r < 4; ++r) {
                int row = row0 + wave_m * 128 + fm * 16 + ((lane >> 4) * 4) + r;
                atomicAdd(&out[(size_t)row * ODIM + col], acc[fm][fn][r]);
            }
        }
    }
}

extern "C" void kernel_launch(void* const* d_in, const int* in_sizes, int n_in,
                              void* d_out, int out_size, void* d_ws, size_t ws_size,
                              hipStream_t stream) {
    (void)in_sizes; (void)n_in; (void)out_size;
    const float* x      = (const float*)d_in[0];
    const float* coeffs = (const float*)d_in[1];
    const float* bias   = (const float*)d_in[2];
    float* out = (float*)d_out;

    const bool use_ws = (ws_size >= WS_NEED) && (((uintptr_t)d_ws & 15) == 0);

    bias_init<<<dim3(2048), dim3(256), 0, stream>>>(bias, out);
    if (use_ws) {
        prep_b<<<dim3(512), dim3(512), 0, stream>>>(coeffs, (short*)d_ws);
        fkan_gemm<1><<<dim3(256), dim3(512), 0, stream>>>(x, coeffs, (const short*)d_ws, out);
    } else {
        fkan_gemm<0><<<dim3(256), dim3(512), 0, stream>>>(x, coeffs, nullptr, out);
    }
}

// Round 5
// 205.957 us; speedup vs baseline: 1.3782x; 1.2021x over previous
//
#include <hip/hip_runtime.h>
#include <hip/hip_bf16.h>

#define IDIM 256
#define GDIM 64
#define ODIM 512
#define KD   (IDIM * GDIM)
#define TILE_SHORTS (512 * 64)
#define WS_NEED ((size_t)512 * TILE_SHORTS * 2)   // 32 MB bf16 image

typedef __attribute__((ext_vector_type(8))) short bhalf8;
typedef __attribute__((ext_vector_type(4))) float fvec4;
typedef __attribute__((ext_vector_type(4))) unsigned uvec4;

#define INV2PI 0.15915494309189535f

static __device__ __forceinline__ short bf16b(float v) {
    __hip_bfloat16 hb = __float2bfloat16(v);
    short s; __builtin_memcpy(&s, &hb, 2); return s;
}
static __device__ __forceinline__ unsigned cvtpk(float lo, float hi) {
    unsigned r;
    asm("v_cvt_pk_bf16_f32 %0, %1, %2" : "=v"(r) : "v"(lo), "v"(hi));
    return r;
}

// ws image, K-permuted: tile b = i*2+h, row o (512), slot = z*32 + Q*8 + u
//   -> coeff[z][o][i][16Q + 8h + u]  (trig multiplier m = 16Q + 8h + u + 1)
// Rows 128 B, XOR-swizzled 16B granules (^(o&7)<<4).
__global__ void prep_b(const float* __restrict__ coeffs, short* __restrict__ ws) {
    const int b = blockIdx.x;          // 512: i*2+h
    const int i = b >> 1, h = b & 1;
    const int o = threadIdx.x;         // 512
    short* dst = ws + ((size_t)b * 512 + o) * 64;
    const int swz = (o & 7) << 4;
#pragma unroll
    for (int j = 0; j < 8; ++j) {      // granule: z = j>>2, Q = j&3
        const int z = j >> 2, Qq = j & 3;
        const float* src = coeffs + ((size_t)z * ODIM + o) * KD
                         + (size_t)i * GDIM + 16 * Qq + 8 * h;
        fvec4 v0 = ((const fvec4*)src)[0];
        fvec4 v1 = ((const fvec4*)src)[1];
        bhalf8 pk;
#pragma unroll
        for (int u = 0; u < 4; ++u) { pk[u] = bf16b(v0[u]); pk[4 + u] = bf16b(v1[u]); }
        *(bhalf8*)((char*)dst + ((j * 16) ^ swz)) = pk;
    }
}

__global__ void bias_init(const float* __restrict__ bias, float* __restrict__ out) {
    int idx = blockIdx.x * 256 + threadIdx.x;
    fvec4 bv = ((const fvec4*)bias)[idx & 127];
    ((fvec4*)out)[idx] = bv;
}

template<int USE_WS>
__global__ void __launch_bounds__(512, 2)
fkan_gemm(const float* __restrict__ x, const float* __restrict__ coeffs,
          const short* __restrict__ wsb, float* __restrict__ out) {
    __shared__ __align__(16) short B_lds[3][256 * 64];   // 96 KB
    __shared__ float xl[256][33];                        // 33 KB

    const int bx = blockIdx.x;
    const int xcd = bx & 7, jj = bx >> 3;
    const int lg = xcd * 2 + (jj & 1);
    const int mt = jj >> 1;
    const int ot = lg >> 3, ks = lg & 7;
    const int row0 = mt * 256, col0 = ot * 256;
    const int i0 = ks * 32;

    const int t = threadIdx.x;
    const int lane = t & 63, wid = t >> 6;
    const int wave_m = wid & 1, wave_n = wid >> 1;

    const int rBb = wave_n * 64 + (lane & 15);
    const int kl  = (lane >> 4) * 16;
    const int msk = (lane & 7) << 4;
    const int rA0 = wave_m * 128 + (lane & 15);
    const float m0f = (float)(16 * (lane >> 4) + 1);   // quarter's first multiplier

    // ---- x panel -> LDS ----
#pragma unroll
    for (int k2 = 0; k2 < 16; ++k2) {
        int idx = t + k2 * 512;
        int r = idx >> 5, c = idx & 31;
        xl[r][c] = x[(size_t)(row0 + r) * IDIM + i0 + c];
    }

    fvec4 acc[8][4];
#pragma unroll
    for (int a = 0; a < 8; ++a)
#pragma unroll
        for (int b = 0; b < 4; ++b) acc[a][b] = (fvec4)0.0f;

    auto dmaB = [&](int j) {
        const short* src = wsb + (size_t)(i0 * 2 + j) * TILE_SHORTS
                         + (size_t)col0 * 64 + (size_t)t * 8;
        const int bsel = j % 3;
#pragma unroll
        for (int q = 0; q < 4; ++q)
            __builtin_amdgcn_global_load_lds(
                (const __attribute__((address_space(1))) unsigned*)(src + q * 4096),
                (__attribute__((address_space(3))) unsigned*)
                    &B_lds[bsel][q * 4096 + wid * 512],
                16, 0, 0);
    };

    auto stage_fb = [&](int T) {
        const int bsel = T % 3;
        const int i = i0 + (T >> 1), hh = T & 1;
        const int o = t >> 1, z = t & 1;
        char* drow = (char*)&B_lds[bsel][o * 64];
        const int swz = (o & 7) << 4;
#pragma unroll
        for (int Qq = 0; Qq < 4; ++Qq) {
            const float* src = coeffs + ((size_t)z * ODIM + col0 + o) * KD
                             + (size_t)i * GDIM + 16 * Qq + 8 * hh;
            fvec4 v0 = ((const fvec4*)src)[0];
            fvec4 v1 = ((const fvec4*)src)[1];
            bhalf8 pk;
#pragma unroll
            for (int u = 0; u < 4; ++u) { pk[u] = bf16b(v0[u]); pk[4 + u] = bf16b(v1[u]); }
            *(bhalf8*)(drow + ((z * 64 + Qq * 16) ^ swz)) = pk;
        }
    };

    // persistent chain state across the two tiles of an i
    float stcA[8], stcB[8], stsA[8], stsB[8], stC2[8];

    // ---- prologue ----
    if (USE_WS) {
        dmaB(0); dmaB(1);
        asm volatile("s_waitcnt vmcnt(4) lgkmcnt(0)" ::: "memory");
        __builtin_amdgcn_s_barrier();
    } else {
        __syncthreads();
    }

#pragma unroll 1
    for (int ii = 0; ii < 32; ++ii) {
#pragma unroll
        for (int h = 0; h < 2; ++h) {
            const int T = 2 * ii + h;
            const int bsel = T % 3;
            if (USE_WS) {
                int j = T + 2; if (j > 63) j = 63;   // clamped re-DMA: same bytes, keeps vmcnt uniform
                dmaB(j);
                __builtin_amdgcn_sched_barrier(0);
            } else {
                stage_fb(T);
                __syncthreads();
            }

            const short* Bb = &B_lds[bsel][0];
            bhalf8 bq[4][2];
#pragma unroll
            for (int fn = 0; fn < 4; ++fn)
#pragma unroll
                for (int ksb = 0; ksb < 2; ++ksb)
                    bq[fn][ksb] = *(const bhalf8*)((const char*)Bb +
                        (size_t)(rBb + fn * 16) * 128 + ((ksb * 64 + kl) ^ msk));

#pragma unroll
            for (int hm = 0; hm < 2; ++hm) {
                unsigned pc[4][4], ps[4][4];
#pragma unroll
                for (int q2 = 0; q2 < 4; ++q2) {
                    const int r = hm * 4 + q2;
                    float cA, cB, sA, sB, C2;
                    if (h == 0) {
                        // seed: T0 = f(m0*x), T1 via rotation by (cos x, sin x)
                        float xv = xl[rA0 + r * 16][ii];
                        float rev = xv * INV2PI;
                        float a0 = __builtin_amdgcn_fractf(rev * m0f);
                        float c0 = __builtin_amdgcn_cosf(a0);
                        float s0 = __builtin_amdgcn_sinf(a0);
                        float a1 = __builtin_amdgcn_fractf(rev);
                        float c1 = __builtin_amdgcn_cosf(a1);
                        float s1 = __builtin_amdgcn_sinf(a1);
                        C2 = c1 + c1;
                        cA = c0; sA = s0;
                        cB = c0 * c1 - s0 * s1;
                        sB = s0 * c1 + c0 * s1;
                        pc[q2][0] = cvtpk(cA, cB);
                        ps[q2][0] = cvtpk(sA, sB);
#pragma unroll
                        for (int p = 1; p < 4; ++p) {
                            float clo = __builtin_fmaf(C2, cB, -cA);
                            float slo = __builtin_fmaf(C2, sB, -sA);
                            cA = cB; cB = clo; sA = sB; sB = slo;
                            float chi = __builtin_fmaf(C2, cB, -cA);
                            float shi = __builtin_fmaf(C2, sB, -sA);
                            cA = cB; cB = chi; sA = sB; sB = shi;
                            pc[q2][p] = cvtpk(clo, chi);
                            ps[q2][p] = cvtpk(slo, shi);
                        }
                        stcA[r] = cA; stcB[r] = cB; stsA[r] = sA; stsB[r] = sB; stC2[r] = C2;
                    } else {
                        cA = stcA[r]; cB = stcB[r]; sA = stsA[r]; sB = stsB[r]; C2 = stC2[r];
#pragma unroll
                        for (int p = 0; p < 4; ++p) {
                            float clo = __builtin_fmaf(C2, cB, -cA);
                            float slo = __builtin_fmaf(C2, sB, -sA);
                            cA = cB; cB = clo; sA = sB; sB = slo;
                            float chi = __builtin_fmaf(C2, cB, -cA);
                            float shi = __builtin_fmaf(C2, sB, -sA);
                            cA = cB; cB = chi; sA = sB; sB = shi;
                            pc[q2][p] = cvtpk(clo, chi);
                            ps[q2][p] = cvtpk(slo, shi);
                        }
                    }
                }
                bhalf8 afc[4], afs[4];
#pragma unroll
                for (int q2 = 0; q2 < 4; ++q2) {
                    uvec4 uc = {pc[q2][0], pc[q2][1], pc[q2][2], pc[q2][3]};
                    uvec4 us = {ps[q2][0], ps[q2][1], ps[q2][2], ps[q2][3]};
                    afc[q2] = __builtin_bit_cast(bhalf8, uc);
                    afs[q2] = __builtin_bit_cast(bhalf8, us);
                }
#pragma unroll
                for (int q2 = 0; q2 < 4; ++q2)
#pragma unroll
                    for (int fn = 0; fn < 4; ++fn) {
                        acc[hm * 4 + q2][fn] = __builtin_amdgcn_mfma_f32_16x16x32_bf16(
                            afc[q2], bq[fn][0], acc[hm * 4 + q2][fn], 0, 0, 0);
                        acc[hm * 4 + q2][fn] = __builtin_amdgcn_mfma_f32_16x16x32_bf16(
                            afs[q2], bq[fn][1], acc[hm * 4 + q2][fn], 0, 0, 0);
                    }
            }

            if (USE_WS) {
                asm volatile("s_waitcnt vmcnt(4)" ::: "memory");
                __builtin_amdgcn_s_barrier();
            } else {
                __syncthreads();
            }
        }
    }

    // epilogue: C/D layout col=lane&15, row=(lane>>4)*4+r
#pragma unroll
    for (int fm = 0; fm < 8; ++fm) {
#pragma unroll
        for (int fn = 0; fn < 4; ++fn) {
            int col = col0 + wave_n * 64 + fn * 16 + (lane & 15);
#pragma unroll
            for (int r = 0; r < 4; ++r) {
                int row = row0 + wave_m * 128 + fm * 16 + ((lane >> 4) * 4) + r;
                atomicAdd(&out[(size_t)row * ODIM + col], acc[fm][fn][r]);
            }
        }
    }
}

extern "C" void kernel_launch(void* const* d_in, const int* in_sizes, int n_in,
                              void* d_out, int out_size, void* d_ws, size_t ws_size,
                              hipStream_t stream) {
    (void)in_sizes; (void)n_in; (void)out_size;
    const float* x      = (const float*)d_in[0];
    const float* coeffs = (const float*)d_in[1];
    const float* bias   = (const float*)d_in[2];
    float* out = (float*)d_out;

    const bool use_ws = (ws_size >= WS_NEED) && (((uintptr_t)d_ws & 15) == 0);

    bias_init<<<dim3(2048), dim3(256), 0, stream>>>(bias, out);
    if (use_ws) {
        prep_b<<<dim3(512), dim3(512), 0, stream>>>(coeffs, (short*)d_ws);
        fkan_gemm<1><<<dim3(256), dim3(512), 0, stream>>>(x, coeffs, (const short*)d_ws, out);
    } else {
        fkan_gemm<0><<<dim3(256), dim3(512), 0, stream>>>(x, coeffs, nullptr, out);
    }
}

// Round 8
// 196.310 us; speedup vs baseline: 1.4459x; 1.0491x over previous
//
#include <hip/hip_runtime.h>
#include <hip/hip_bf16.h>

#define IDIM 256
#define GDIM 64
#define ODIM 512
#define KD   (IDIM * GDIM)
#define TILE_SHORTS (512 * 64)
#define WS_NEED ((size_t)512 * TILE_SHORTS * 2)   // 32 MB bf16 image

typedef __attribute__((ext_vector_type(8))) short bhalf8;
typedef __attribute__((ext_vector_type(4))) float fvec4;
typedef __attribute__((ext_vector_type(4))) unsigned uvec4;

#define INV2PI 0.15915494309189535f

static __device__ __forceinline__ short bf16b(float v) {
    __hip_bfloat16 hb = __float2bfloat16(v);
    short s; __builtin_memcpy(&s, &hb, 2); return s;
}
static __device__ __forceinline__ unsigned cvtpk(float lo, float hi) {
    unsigned r;
    asm("v_cvt_pk_bf16_f32 %0, %1, %2" : "=v"(r) : "v"(lo), "v"(hi));
    return r;
}

// ws image, K-permuted: tile b = i*2+h, row o (512), slot = z*32 + Q*8 + u
//   -> coeff[z][o][i][16Q + 8h + u]  (trig multiplier m = 16Q + 8h + u + 1)
// Rows 128 B, XOR-swizzled 16B granules (^(o&7)<<4).  [proven R3-R5]
__global__ void prep_b(const float* __restrict__ coeffs, short* __restrict__ ws) {
    const int b = blockIdx.x;          // 512: i*2+h
    const int i = b >> 1, h = b & 1;
    const int o = threadIdx.x;         // 512
    short* dst = ws + ((size_t)b * 512 + o) * 64;
    const int swz = (o & 7) << 4;
#pragma unroll
    for (int j = 0; j < 8; ++j) {      // granule: z = j>>2, Q = j&3
        const int z = j >> 2, Qq = j & 3;
        const float* src = coeffs + ((size_t)z * ODIM + o) * KD
                         + (size_t)i * GDIM + 16 * Qq + 8 * h;
        fvec4 v0 = ((const fvec4*)src)[0];
        fvec4 v1 = ((const fvec4*)src)[1];
        bhalf8 pk;
#pragma unroll
        for (int u = 0; u < 4; ++u) { pk[u] = bf16b(v0[u]); pk[4 + u] = bf16b(v1[u]); }
        *(bhalf8*)((char*)dst + ((j * 16) ^ swz)) = pk;
    }
}

__global__ void bias_init(const float* __restrict__ bias, float* __restrict__ out) {
    int idx = blockIdx.x * 256 + threadIdx.x;
    fvec4 bv = ((const fvec4*)bias)[idx & 127];
    ((fvec4*)out)[idx] = bv;
}

// Fence: asm drain (LDS-DMA is vmcnt; fence lowering may not cover its LDS
// aliasing) + sched_barrier pin + __syncthreads (IR-level ordering + barrier).
#define FENCE() do { asm volatile("s_waitcnt vmcnt(0) lgkmcnt(0)" ::: "memory"); \
                     __builtin_amdgcn_sched_barrier(0); \
                     __syncthreads(); } while (0)

// 1024 blocks = 32 mt x 4 ot x 8 ks = exactly 4 blocks/CU (16 waves/CU).
// Block: 256 thr (2x2 waves), output 128x128, wave tile 64x64 (acc 64 VGPR).
// K-chunk: 32 i's = 64 tiles; B double-buffered DMA (issue at tile top, full
// drain at tile end). A in-register Chebyshev from cooperative seed panel.
template<int USE_WS>
__global__ void __launch_bounds__(256, 4)
fkan_gemm(const float* __restrict__ x, const float* __restrict__ coeffs,
          const short* __restrict__ wsb, float* __restrict__ out) {
    __shared__ __align__(16) short B_lds[2][128 * 64];   // 32 KB
    __shared__ float  sl_rev[4][128];                    // 2 KB
    __shared__ float2 sl_cs[4][128];                     // 4 KB

    const int bx = blockIdx.x;            // 0..1023
    const int xcd = bx & 7, j = bx >> 3;  // j 0..127
    const int lg  = xcd * 4 + (j & 3);    // 0..31 = (ot,ks), 4 groups per XCD
    const int mt  = j >> 2;               // 0..31
    const int ot  = lg >> 3, ks = lg & 7;
    const int row0 = mt * 128, col0 = ot * 128;
    const int i0 = ks * 32;

    const int t = threadIdx.x;
    const int lane = t & 63, wid = t >> 6;           // 4 waves
    const int wave_m = wid & 1, wave_n = wid >> 1;   // 2 x 2

    const int rBb = wave_n * 64 + (lane & 15);       // B row (local col)
    const int kl  = (lane >> 4) * 16;
    const int msk = (lane & 7) << 4;
    const int rA0 = wave_m * 64 + (lane & 15);       // A local row base
    const float m0base = (float)(16 * (lane >> 4) + 1);

    fvec4 acc[4][4];
#pragma unroll
    for (int a = 0; a < 4; ++a)
#pragma unroll
        for (int b = 0; b < 4; ++b) acc[a][b] = (fvec4)0.0f;

    // cooperative seed panel: (rev, cos x, sin x) per (row, i), 4 i's per chunk
    auto fill_sl = [&](int chunk) {
#pragma unroll
        for (int w = 0; w < 2; ++w) {
            int idx = t + w * 256;            // 0..511
            int il2 = idx & 3, r2 = idx >> 2; // r2 0..127
            float xv = x[(size_t)(row0 + r2) * IDIM + i0 + chunk * 4 + il2];
            float rev = xv * INV2PI;
            float a = __builtin_amdgcn_fractf(rev);
            float2 cs;
            cs.x = __builtin_amdgcn_cosf(a);
            cs.y = __builtin_amdgcn_sinf(a);
            sl_rev[il2][r2] = rev;
            sl_cs[il2][r2] = cs;
        }
    };

    auto dmaB = [&](int T1) {
        const short* src = wsb + (size_t)(i0 * 2 + T1) * TILE_SHORTS
                         + (size_t)col0 * 64 + (size_t)t * 8;
        const int bsel = T1 & 1;
#pragma unroll
        for (int q = 0; q < 4; ++q)
            __builtin_amdgcn_global_load_lds(
                (const __attribute__((address_space(1))) unsigned*)(src + q * 2048),
                (__attribute__((address_space(3))) unsigned*)
                    &B_lds[bsel][q * 2048 + wid * 512],
                16, 0, 0);
    };

    auto stage_fb = [&](int T1) {   // fallback staging (no ws)
        const int bsel = T1 & 1;
        const int i = i0 + (T1 >> 1), hh = T1 & 1;
        const int o = t >> 1, z = t & 1;   // o 0..127
        char* drow = (char*)&B_lds[bsel][o * 64];
        const int swz = (o & 7) << 4;
#pragma unroll
        for (int Qq = 0; Qq < 4; ++Qq) {
            const float* src = coeffs + ((size_t)z * ODIM + col0 + o) * KD
                             + (size_t)i * GDIM + 16 * Qq + 8 * hh;
            fvec4 v0 = ((const fvec4*)src)[0];
            fvec4 v1 = ((const fvec4*)src)[1];
            bhalf8 pk;
#pragma unroll
            for (int u = 0; u < 4; ++u) { pk[u] = bf16b(v0[u]); pk[4 + u] = bf16b(v1[u]); }
            *(bhalf8*)(drow + ((z * 64 + Qq * 16) ^ swz)) = pk;
        }
    };

    // ---- prologue ----
    fill_sl(0);
    if (USE_WS) dmaB(0);
    FENCE();

#pragma unroll 1
    for (int T = 0; T < 64; ++T) {
        if ((T & 7) == 0 && T > 0) {
            fill_sl(T >> 3);
            FENCE();
        }
        if (USE_WS) {
            if (T < 63) dmaB(T + 1);     // opposite buffer; lands during compute
            __builtin_amdgcn_sched_barrier(0);
        } else {
            stage_fb(T);
            FENCE();
        }

        const int bsel = T & 1;
        const int il = (T >> 1) & 3;
        const float m0h = m0base + (float)((T & 1) * 8);
        const short* Bb = &B_lds[bsel][0];

        // ---- cos phase: seeds + cos chains -> afc; MFMA with B k-slots 0..31 ----
        float c_sA[4], c_sB[4], c_C2[4];
        bhalf8 afc[4];
#pragma unroll
        for (int fm = 0; fm < 4; ++fm) {
            const int rr = rA0 + fm * 16;
            float rev = sl_rev[il][rr];
            float2 cs1 = sl_cs[il][rr];
            float C2 = cs1.x + cs1.x;
            float a0 = __builtin_amdgcn_fractf(rev * m0h);
            float c0 = __builtin_amdgcn_cosf(a0);
            float s0 = __builtin_amdgcn_sinf(a0);
            float cA = c0;
            float cB = __builtin_fmaf(c0, cs1.x, -(s0 * cs1.y));   // cos((m0+1)x)
            float sB = __builtin_fmaf(s0, cs1.x,  (c0 * cs1.y));   // sin((m0+1)x)
            c_sA[fm] = s0; c_sB[fm] = sB; c_C2[fm] = C2;
            uvec4 uc;
            uc[0] = cvtpk(cA, cB);
#pragma unroll
            for (int p = 1; p < 4; ++p) {
                float cn = __builtin_fmaf(C2, cB, -cA); cA = cB; cB = cn;
                cn = __builtin_fmaf(C2, cB, -cA); cA = cB; cB = cn;
                uc[p] = cvtpk(cA, cB);
            }
            afc[fm] = __builtin_bit_cast(bhalf8, uc);
        }
        {
            bhalf8 bq[4];
#pragma unroll
            for (int fn = 0; fn < 4; ++fn)
                bq[fn] = *(const bhalf8*)((const char*)Bb +
                    (size_t)(rBb + fn * 16) * 128 + (kl ^ msk));
            __builtin_amdgcn_s_setprio(1);
#pragma unroll
            for (int fm = 0; fm < 4; ++fm)
#pragma unroll
                for (int fn = 0; fn < 4; ++fn)
                    acc[fm][fn] = __builtin_amdgcn_mfma_f32_16x16x32_bf16(
                        afc[fm], bq[fn], acc[fm][fn], 0, 0, 0);
            __builtin_amdgcn_s_setprio(0);
        }

        // ---- sin phase: chains from carried seeds -> afs; B k-slots 32..63 ----
        bhalf8 afs[4];
#pragma unroll
        for (int fm = 0; fm < 4; ++fm) {
            float C2 = c_C2[fm];
            float sA = c_sA[fm], sB = c_sB[fm];
            uvec4 us;
            us[0] = cvtpk(sA, sB);
#pragma unroll
            for (int p = 1; p < 4; ++p) {
                float sn = __builtin_fmaf(C2, sB, -sA); sA = sB; sB = sn;
                sn = __builtin_fmaf(C2, sB, -sA); sA = sB; sB = sn;
                us[p] = cvtpk(sA, sB);
            }
            afs[fm] = __builtin_bit_cast(bhalf8, us);
        }
        {
            bhalf8 bq[4];
#pragma unroll
            for (int fn = 0; fn < 4; ++fn)
                bq[fn] = *(const bhalf8*)((const char*)Bb +
                    (size_t)(rBb + fn * 16) * 128 + ((64 + kl) ^ msk));
            __builtin_amdgcn_s_setprio(1);
#pragma unroll
            for (int fm = 0; fm < 4; ++fm)
#pragma unroll
                for (int fn = 0; fn < 4; ++fn)
                    acc[fm][fn] = __builtin_amdgcn_mfma_f32_16x16x32_bf16(
                        afs[fm], bq[fn], acc[fm][fn], 0, 0, 0);
            __builtin_amdgcn_s_setprio(0);
        }

        FENCE();   // drain DMA(T+1) + publish; belt-and-suspenders ordering
    }

    // epilogue: C/D layout col=lane&15, row=(lane>>4)*4+r
#pragma unroll
    for (int fm = 0; fm < 4; ++fm) {
#pragma unroll
        for (int fn = 0; fn < 4; ++fn) {
            int col = col0 + wave_n * 64 + fn * 16 + (lane & 15);
#pragma unroll
            for (int r = 0; r < 4; ++r) {
                int row = row0 + wave_m * 64 + fm * 16 + ((lane >> 4) * 4) + r;
                atomicAdd(&out[(size_t)row * ODIM + col], acc[fm][fn][r]);
            }
        }
    }
}

extern "C" void kernel_launch(void* const* d_in, const int* in_sizes, int n_in,
                              void* d_out, int out_size, void* d_ws, size_t ws_size,
                              hipStream_t stream) {
    (void)in_sizes; (void)n_in; (void)out_size;
    const float* x      = (const float*)d_in[0];
    const float* coeffs = (const float*)d_in[1];
    const float* bias   = (const float*)d_in[2];
    float* out = (float*)d_out;

    const bool use_ws = (ws_size >= WS_NEED) && (((uintptr_t)d_ws & 15) == 0);

    bias_init<<<dim3(2048), dim3(256), 0, stream>>>(bias, out);
    if (use_ws) {
        prep_b<<<dim3(512), dim3(512), 0, stream>>>(coeffs, (short*)d_ws);
        fkan_gemm<1><<<dim3(1024), dim3(256), 0, stream>>>(x, coeffs, (const short*)d_ws, out);
    } else {
        fkan_gemm<0><<<dim3(1024), dim3(256), 0, stream>>>(x, coeffs, nullptr, out);
    }
}

// Round 9
// 176.698 us; speedup vs baseline: 1.6064x; 1.1110x over previous
//
#include <hip/hip_runtime.h>
#include <hip/hip_bf16.h>

#define IDIM 256
#define GDIM 64
#define ODIM 512
#define KD   (IDIM * GDIM)
#define TILE_SHORTS (512 * 64)
#define WS_NEED ((size_t)512 * TILE_SHORTS * 2)   // 32 MB bf16 image

typedef __attribute__((ext_vector_type(8))) short bhalf8;
typedef __attribute__((ext_vector_type(4))) float fvec4;
typedef __attribute__((ext_vector_type(4))) unsigned uvec4;

#define INV2PI 0.15915494309189535f

static __device__ __forceinline__ short bf16b(float v) {
    __hip_bfloat16 hb = __float2bfloat16(v);
    short s; __builtin_memcpy(&s, &hb, 2); return s;
}
static __device__ __forceinline__ unsigned cvtpk(float lo, float hi) {
    unsigned r;
    asm("v_cvt_pk_bf16_f32 %0, %1, %2" : "=v"(r) : "v"(lo), "v"(hi));
    return r;
}

// ws image, K-permuted: tile b = i*2+h, row o (512), slot = z*32 + Q*8 + u
//   -> coeff[z][o][i][16Q + 8h + u]  (trig multiplier m = 16Q + 8h + u + 1)
// Rows 128 B, XOR-swizzled 16B granules (^(o&7)<<4).  [proven R3-R5, R8]
__global__ void prep_b(const float* __restrict__ coeffs, short* __restrict__ ws) {
    const int b = blockIdx.x;          // 512: i*2+h
    const int i = b >> 1, h = b & 1;
    const int o = threadIdx.x;         // 512
    short* dst = ws + ((size_t)b * 512 + o) * 64;
    const int swz = (o & 7) << 4;
#pragma unroll
    for (int j = 0; j < 8; ++j) {      // granule: z = j>>2, Q = j&3
        const int z = j >> 2, Qq = j & 3;
        const float* src = coeffs + ((size_t)z * ODIM + o) * KD
                         + (size_t)i * GDIM + 16 * Qq + 8 * h;
        fvec4 v0 = ((const fvec4*)src)[0];
        fvec4 v1 = ((const fvec4*)src)[1];
        bhalf8 pk;
#pragma unroll
        for (int u = 0; u < 4; ++u) { pk[u] = bf16b(v0[u]); pk[4 + u] = bf16b(v1[u]); }
        *(bhalf8*)((char*)dst + ((j * 16) ^ swz)) = pk;
    }
}

__global__ void bias_init(const float* __restrict__ bias, float* __restrict__ out) {
    int idx = blockIdx.x * 256 + threadIdx.x;
    fvec4 bv = ((const fvec4*)bias)[idx & 127];
    ((fvec4*)out)[idx] = bv;
}

// Fence proven in R8: asm drain of LDS-DMA (vmcnt) + sched pin + __syncthreads.
#define FENCE() do { asm volatile("s_waitcnt vmcnt(0) lgkmcnt(0)" ::: "memory"); \
                     __builtin_amdgcn_sched_barrier(0); \
                     __syncthreads(); } while (0)

// chain advance: two Chebyshev steps for cos & sin (same C2)
#define ADV2(cA,cB,sA,sB,C2) do { \
    float _cn = __builtin_fmaf((C2),(cB),-(cA)); (cA)=(cB); (cB)=_cn; \
    float _sn = __builtin_fmaf((C2),(sB),-(sA)); (sA)=(sB); (sB)=_sn; \
    _cn = __builtin_fmaf((C2),(cB),-(cA)); (cA)=(cB); (cB)=_cn; \
    _sn = __builtin_fmaf((C2),(sB),-(sA)); (sA)=(sB); (sB)=_sn; } while (0)

// 1024 blocks = 32 mt x 4 ot x 8 ks = 4 blocks/CU. Block: 256 thr = 4 waves,
// 1x4 wave grid: each wave owns 32 DISTINCT rows x 128 cols (acc[2][8]) -- no
// cross-wave trig duplication. Chain state carried across the two h-tiles of
// each i: transcendental seeds only on even tiles (6 trans/wave/i).
template<int USE_WS>
__global__ void __launch_bounds__(256, 4)
fkan_gemm(const float* __restrict__ x, const float* __restrict__ coeffs,
          const short* __restrict__ wsb, float* __restrict__ out) {
    __shared__ __align__(16) short B_lds[2][128 * 64];   // 32 KB
    __shared__ float  sl_rev[4][128];                    // 2 KB
    __shared__ float2 sl_cs[4][128];                     // 4 KB

    const int bx = blockIdx.x;            // 0..1023
    const int xcd = bx & 7, j = bx >> 3;  // j 0..127
    const int lg  = xcd * 4 + (j & 3);    // 0..31 = (ot,ks), 4 groups per XCD
    const int mt  = j >> 2;               // 0..31
    const int ot  = lg >> 3, ks = lg & 7;
    const int row0 = mt * 128, col0 = ot * 128;
    const int i0 = ks * 32;

    const int t = threadIdx.x;
    const int lane = t & 63, wid = t >> 6;   // 4 waves, 1x4: rows wid*32..+31
    const int kl  = (lane >> 4) * 16;
    const int msk = (lane & 7) << 4;
    const int rA0 = wid * 32 + (lane & 15);
    const float m0f = (float)(16 * (lane >> 4) + 1);

    fvec4 acc[2][8];
#pragma unroll
    for (int a = 0; a < 2; ++a)
#pragma unroll
        for (int b = 0; b < 8; ++b) acc[a][b] = (fvec4)0.0f;

    // cooperative seed panel: (rev, cos x, sin x) per (row, i), 4 i's per chunk
    auto fill_sl = [&](int chunk) {
#pragma unroll
        for (int w = 0; w < 2; ++w) {
            int idx = t + w * 256;            // 0..511
            int il2 = idx & 3, r2 = idx >> 2; // r2 0..127
            float xv = x[(size_t)(row0 + r2) * IDIM + i0 + chunk * 4 + il2];
            float rev = xv * INV2PI;
            float a = __builtin_amdgcn_fractf(rev);
            float2 cs;
            cs.x = __builtin_amdgcn_cosf(a);
            cs.y = __builtin_amdgcn_sinf(a);
            sl_rev[il2][r2] = rev;
            sl_cs[il2][r2] = cs;
        }
    };

    auto dmaB = [&](int T1) {
        const short* src = wsb + (size_t)(i0 * 2 + T1) * TILE_SHORTS
                         + (size_t)col0 * 64 + (size_t)t * 8;
        const int bsel = T1 & 1;
#pragma unroll
        for (int q = 0; q < 4; ++q)
            __builtin_amdgcn_global_load_lds(
                (const __attribute__((address_space(1))) unsigned*)(src + q * 2048),
                (__attribute__((address_space(3))) unsigned*)
                    &B_lds[bsel][q * 2048 + wid * 512],
                16, 0, 0);
    };

    auto stage_fb = [&](int T1) {   // fallback staging (no ws)
        const int bsel = T1 & 1;
        const int i = i0 + (T1 >> 1), hh = T1 & 1;
        const int o = t >> 1, z = t & 1;   // o 0..127
        char* drow = (char*)&B_lds[bsel][o * 64];
        const int swz = (o & 7) << 4;
#pragma unroll
        for (int Qq = 0; Qq < 4; ++Qq) {
            const float* src = coeffs + ((size_t)z * ODIM + col0 + o) * KD
                             + (size_t)i * GDIM + 16 * Qq + 8 * hh;
            fvec4 v0 = ((const fvec4*)src)[0];
            fvec4 v1 = ((const fvec4*)src)[1];
            bhalf8 pk;
#pragma unroll
            for (int u = 0; u < 4; ++u) { pk[u] = bf16b(v0[u]); pk[4 + u] = bf16b(v1[u]); }
            *(bhalf8*)(drow + ((z * 64 + Qq * 16) ^ swz)) = pk;
        }
    };

    // ---- prologue ----
    fill_sl(0);
    if (USE_WS) dmaB(0);
    FENCE();

    // chain state, statically indexed (fm fully unrolled)
    float ccA0, ccB0, csA0, csB0, cC20;
    float ccA1, ccB1, csA1, csB1, cC21;

#pragma unroll 1
    for (int T = 0; T < 64; ++T) {
        if ((T & 7) == 0 && T > 0) {
            fill_sl(T >> 3);
            FENCE();
        }
        if (USE_WS) {
            if (T < 63) dmaB(T + 1);     // opposite buffer; lands during compute
            __builtin_amdgcn_sched_barrier(0);
        } else {
            stage_fb(T);
            FENCE();
        }

        const int bsel = T & 1;
        const int il = (T >> 1) & 3;
        const short* Bb = &B_lds[bsel][0];

        // ---- A fragments: Chebyshev chain, seeded on even tiles only ----
        bhalf8 afc[2], afs[2];
        if ((T & 1) == 0) {
#pragma unroll
            for (int fm = 0; fm < 2; ++fm) {
                const int rr = rA0 + fm * 16;
                float rev = sl_rev[il][rr];
                float2 cs1 = sl_cs[il][rr];
                float C2 = cs1.x + cs1.x;
                float a0 = __builtin_amdgcn_fractf(rev * m0f);
                float cA = __builtin_amdgcn_cosf(a0);        // cos(m0 x)
                float sA = __builtin_amdgcn_sinf(a0);
                float cB = __builtin_fmaf(cA, cs1.x, -(sA * cs1.y));  // m0+1
                float sB = __builtin_fmaf(sA, cs1.x,  (cA * cs1.y));
                uvec4 uc, us;
                uc[0] = cvtpk(cA, cB); us[0] = cvtpk(sA, sB);
#pragma unroll
                for (int p = 1; p < 4; ++p) {
                    ADV2(cA, cB, sA, sB, C2);
                    uc[p] = cvtpk(cA, cB); us[p] = cvtpk(sA, sB);
                }
                if (fm == 0) { ccA0 = cA; ccB0 = cB; csA0 = sA; csB0 = sB; cC20 = C2; }
                else         { ccA1 = cA; ccB1 = cB; csA1 = sA; csB1 = sB; cC21 = C2; }
                afc[fm] = __builtin_bit_cast(bhalf8, uc);
                afs[fm] = __builtin_bit_cast(bhalf8, us);
            }
        } else {
#pragma unroll
            for (int fm = 0; fm < 2; ++fm) {
                float cA = fm ? ccA1 : ccA0, cB = fm ? ccB1 : ccB0;
                float sA = fm ? csA1 : csA0, sB = fm ? csB1 : csB0;
                float C2 = fm ? cC21 : cC20;
                uvec4 uc, us;
#pragma unroll
                for (int p = 0; p < 4; ++p) {
                    ADV2(cA, cB, sA, sB, C2);
                    uc[p] = cvtpk(cA, cB); us[p] = cvtpk(sA, sB);
                }
                afc[fm] = __builtin_bit_cast(bhalf8, uc);
                afs[fm] = __builtin_bit_cast(bhalf8, us);
            }
        }

        // ---- MFMA: per 64-col half, cos block then sin block (bq reuse) ----
#pragma unroll
        for (int half = 0; half < 2; ++half) {
            bhalf8 bq[4];
#pragma unroll
            for (int f4 = 0; f4 < 4; ++f4)
                bq[f4] = *(const bhalf8*)((const char*)Bb +
                    (size_t)(half * 64 + f4 * 16 + (lane & 15)) * 128 + (kl ^ msk));
            __builtin_amdgcn_s_setprio(1);
#pragma unroll
            for (int fm = 0; fm < 2; ++fm)
#pragma unroll
                for (int f4 = 0; f4 < 4; ++f4)
                    acc[fm][half * 4 + f4] = __builtin_amdgcn_mfma_f32_16x16x32_bf16(
                        afc[fm], bq[f4], acc[fm][half * 4 + f4], 0, 0, 0);
            __builtin_amdgcn_s_setprio(0);
#pragma unroll
            for (int f4 = 0; f4 < 4; ++f4)
                bq[f4] = *(const bhalf8*)((const char*)Bb +
                    (size_t)(half * 64 + f4 * 16 + (lane & 15)) * 128 + ((64 + kl) ^ msk));
            __builtin_amdgcn_s_setprio(1);
#pragma unroll
            for (int fm = 0; fm < 2; ++fm)
#pragma unroll
                for (int f4 = 0; f4 < 4; ++f4)
                    acc[fm][half * 4 + f4] = __builtin_amdgcn_mfma_f32_16x16x32_bf16(
                        afs[fm], bq[f4], acc[fm][half * 4 + f4], 0, 0, 0);
            __builtin_amdgcn_s_setprio(0);
        }

        FENCE();   // drain DMA(T+1) + publish
    }

    // epilogue: C/D layout col=lane&15, row=(lane>>4)*4+r
#pragma unroll
    for (int fm = 0; fm < 2; ++fm) {
#pragma unroll
        for (int f = 0; f < 8; ++f) {
            int col = col0 + f * 16 + (lane & 15);
#pragma unroll
            for (int r = 0; r < 4; ++r) {
                int row = row0 + wid * 32 + fm * 16 + ((lane >> 4) * 4) + r;
                atomicAdd(&out[(size_t)row * ODIM + col], acc[fm][f][r]);
            }
        }
    }
}

extern "C" void kernel_launch(void* const* d_in, const int* in_sizes, int n_in,
                              void* d_out, int out_size, void* d_ws, size_t ws_size,
                              hipStream_t stream) {
    (void)in_sizes; (void)n_in; (void)out_size;
    const float* x      = (const float*)d_in[0];
    const float* coeffs = (const float*)d_in[1];
    const float* bias   = (const float*)d_in[2];
    float* out = (float*)d_out;

    const bool use_ws = (ws_size >= WS_NEED) && (((uintptr_t)d_ws & 15) == 0);

    bias_init<<<dim3(2048), dim3(256), 0, stream>>>(bias, out);
    if (use_ws) {
        prep_b<<<dim3(512), dim3(512), 0, stream>>>(coeffs, (short*)d_ws);
        fkan_gemm<1><<<dim3(1024), dim3(256), 0, stream>>>(x, coeffs, (const short*)d_ws, out);
    } else {
        fkan_gemm<0><<<dim3(1024), dim3(256), 0, stream>>>(x, coeffs, nullptr, out);
    }
}